// Round 1
// 320.406 us; speedup vs baseline: 1.0044x; 1.0044x over previous
//
#include <hip/hip_runtime.h>
#include <hip/hip_bf16.h>

// MultiheadAttention with relative position bias, MI355X gfx950.
// L=1024, B=16, E=512, H=8, d=64. Inputs/output fp32; ws intermediates fp16.
//
// Stage 1: qkv_kernel   -- MFMA in_proj GEMMs -> Q,K,V fp16, (B,H,L,64), q pre-scaled 1/8
//                          R8: global_load_lds(16B) fp32 staging + XOR chunk swizzle
// Stage 2: transpose_v  -- V (B,H,L,64) -> Vt (B,H,64,L) for MFMA B-operand
// Stage 3: attn_kernel  -- MFMA flash attention w/ RPE bias -> CTX fp16 (L,B,E)
// Stage 4: out_kernel   -- MFMA out_proj GEMM -> fp32 output (L,B,E)
//                          R8: same DMA staging (A f16 direct, B fp32)
//
// ws (fp16 elems): Q @0, K @8M, Vt @16M, Vtmp/CTX @24M (aliased, disjoint lifetimes).
//
// MFMA f16 16x16x32 layouts (verified end-to-end in this problem, round 4):
//   A[m=lane&15][k=quad*8+j], B[k=quad*8+j][n=lane&15], D[row=quad*4+reg][col=lane&15]
//
// LDS swizzle (rule 21: linear DMA dest + inverse-swizzled global src + swizzled read):
//   fp32 tile row = 32 f32 = 128 B = 8x16B chunks; logical chunk c at slot c^(row&7)
//   f16  tile row = 32 f16 =  64 B = 4x16B chunks; logical chunk c at slot c^((row>>1)&3)

#define L_SEQ 1024
#define B_N   16
#define E_DIM 512
#define H_N   8
#define NREL  2047

typedef _Float16 f16;
using half8   = __attribute__((ext_vector_type(8))) _Float16;
using floatx4 = __attribute__((ext_vector_type(4))) float;

__device__ __forceinline__ half8 cvt8(const float4 a, const float4 b) {
    half8 h;
    h[0] = (f16)a.x; h[1] = (f16)a.y; h[2] = (f16)a.z; h[3] = (f16)a.w;
    h[4] = (f16)b.x; h[5] = (f16)b.y; h[6] = (f16)b.z; h[7] = (f16)b.w;
    return h;
}

// async global->LDS, 16B per lane. LDS dest is wave-uniform base + lane*16.
__device__ __forceinline__ void gl_lds16(const void* g, void* l) {
    __builtin_amdgcn_global_load_lds(
        (const __attribute__((address_space(1))) unsigned int*)g,
        (__attribute__((address_space(3))) unsigned int*)l,
        16, 0, 0);
}

// ---------------------------------------------------------------------------
// Stage 1: in_proj MFMA GEMM. 1536 blocks, XCD-swizzled so the 4 f-tile
// blocks sharing an X row-slice land on one XCD (same L2).
// ---------------------------------------------------------------------------
__global__ __launch_bounds__(256) void qkv_kernel(
    const float* __restrict__ Xq, const float* __restrict__ Xk, const float* __restrict__ Xv,
    const float* __restrict__ W, const float* __restrict__ Bias,
    f16* __restrict__ Qo, f16* __restrict__ Ko, f16* __restrict__ Vo)
{
    // swizzle: xcd = flat&7; 48 groups (m,proj) per XCD; 4 f-tiles per group
    const int flat = blockIdx.x;
    const int xcd  = flat & 7;
    const int slot = flat >> 3;            // 0..191
    const int g    = xcd * 48 + (slot >> 2);   // 0..383 = proj*128 + mtile
    const int f0   = (slot & 3) << 7;
    const int proj = g >> 7;               // 0=q 1=k 2=v
    const int n0   = (g & 127) << 7;

    const float* X  = (proj == 0) ? Xq : (proj == 1) ? Xk : Xv;
    const float* Wp = W + (size_t)(proj << 9) * E_DIM;

    // fp32 tiles, 128 rows x 32 f32 (128 B/row), linear for DMA. 16 KB each.
    __shared__ __align__(16) float As[128 * 32];
    __shared__ __align__(16) float Bs[128 * 32];

    const int tid  = threadIdx.x;
    const int w    = tid >> 6;
    const int lane = tid & 63;
    const int quad = lane >> 4, c = lane & 15;
    const int wm = (w >> 1) << 6, wn = (w & 1) << 6;

    // staging decomposition: issue i covers rows i*32 + w*8 + (lane>>3),
    // 16B chunk slot lane&7 holds logical chunk (lane&7)^(lane>>3)
    const int lr = lane >> 3;                    // 0..7
    const int lc = (lane & 7) ^ lr;              // inverse-swizzled source chunk
    const float* Xg = X  + (size_t)(n0 + (w << 3) + lr) * E_DIM + (lc << 2);
    const float* Wg = Wp + (size_t)(f0 + (w << 3) + lr) * E_DIM + (lc << 2);

    // fragment-read swizzle: row r (r&7 == c&7), chunks 2q,2q+1 at slots ^(c&7)
    const int sa0 = (((quad << 1) ^ (c & 7)) << 2);  // f32 elem offset of first chunk
    const int sa1 = sa0 ^ 4;

    floatx4 acc[4][4] = {};

    for (int k0 = 0; k0 < E_DIM; k0 += 32) {
        __syncthreads();                   // all waves done reading prev tile
#pragma unroll
        for (int i = 0; i < 4; ++i) {
            gl_lds16(Xg + (size_t)i * (32 * E_DIM) + k0, &As[((i << 5) + (w << 3)) << 5]);
            gl_lds16(Wg + (size_t)i * (32 * E_DIM) + k0, &Bs[((i << 5) + (w << 3)) << 5]);
        }
        __syncthreads();                   // vmcnt drain -> tile ready

        half8 a[4], bfr[4];
#pragma unroll
        for (int mt = 0; mt < 4; ++mt) {
            const int r = (wm + mt * 16 + c) << 5;
            const float4 lo = *reinterpret_cast<const float4*>(&As[r + sa0]);
            const float4 hi = *reinterpret_cast<const float4*>(&As[r + sa1]);
            a[mt] = cvt8(lo, hi);
        }
#pragma unroll
        for (int nt = 0; nt < 4; ++nt) {
            const int r = (wn + nt * 16 + c) << 5;
            const float4 lo = *reinterpret_cast<const float4*>(&Bs[r + sa0]);
            const float4 hi = *reinterpret_cast<const float4*>(&Bs[r + sa1]);
            bfr[nt] = cvt8(lo, hi);
        }
#pragma unroll
        for (int mt = 0; mt < 4; ++mt)
#pragma unroll
            for (int nt = 0; nt < 4; ++nt)
                acc[mt][nt] = __builtin_amdgcn_mfma_f32_16x16x32_f16(a[mt], bfr[nt], acc[mt][nt], 0, 0, 0);
    }

    f16* Dst = (proj == 0) ? Qo : (proj == 1) ? Ko : Vo;
    const float scale = (proj == 0) ? 0.125f : 1.0f;

#pragma unroll
    for (int nt = 0; nt < 4; ++nt) {
        const int fl = f0 + wn + nt * 16 + c;
        const float bj = Bias[(proj << 9) + fl];
        const int h = fl >> 6, d = fl & 63;
#pragma unroll
        for (int mt = 0; mt < 4; ++mt) {
#pragma unroll
            for (int r = 0; r < 4; ++r) {
                const int n = n0 + wm + mt * 16 + quad * 4 + r;
                const int l = n >> 4, b = n & 15;
                Dst[((((size_t)b * H_N + h) * L_SEQ + l) << 6) + d] =
                    (f16)((acc[mt][nt][r] + bj) * scale);
            }
        }
    }
}

// ---------------------------------------------------------------------------
// Stage 2: V (b,h)[l][d] -> Vt (b,h)[d][l]. grid (16, 128), block 256.
// ---------------------------------------------------------------------------
__global__ __launch_bounds__(256) void transpose_v(
    const f16* __restrict__ V, f16* __restrict__ Vt)
{
    const int l0 = blockIdx.x << 6;
    const size_t base = (size_t)blockIdx.y << 16;
    __shared__ __align__(16) f16 T[64][72];
    const int tid = threadIdx.x;
    const int r = tid >> 2, co = (tid & 3) << 4;

    const uint4 a0 = *reinterpret_cast<const uint4*>(V + base + (size_t)(l0 + r) * 64 + co);
    const uint4 a1 = *reinterpret_cast<const uint4*>(V + base + (size_t)(l0 + r) * 64 + co + 8);
    *reinterpret_cast<uint4*>(&T[r][co])     = a0;
    *reinterpret_cast<uint4*>(&T[r][co + 8]) = a1;
    __syncthreads();

    union { f16 h[16]; uint4 u[2]; } pk;
#pragma unroll
    for (int j = 0; j < 16; ++j) pk.h[j] = T[co + j][r];
    *reinterpret_cast<uint4*>(Vt + base + (size_t)r * 1024 + l0 + co)     = pk.u[0];
    *reinterpret_cast<uint4*>(Vt + base + (size_t)r * 1024 + l0 + co + 8) = pk.u[1];
}

// ---------------------------------------------------------------------------
// Stage 3: MFMA flash attention, fixed-max softmax. grid (8, 128), block 256.
// ---------------------------------------------------------------------------
__global__ __launch_bounds__(256, 3) void attn_kernel(
    const f16* __restrict__ Q, const f16* __restrict__ K, const f16* __restrict__ Vt,
    const int* __restrict__ RPE, const float* __restrict__ Tab, f16* __restrict__ CTX)
{
    const int q0 = blockIdx.x << 7;
    const int bh = blockIdx.y;
    const int b = bh >> 3, h = bh & 7;

    const int tid  = threadIdx.x;
    const int w    = tid >> 6;
    const int lane = tid & 63;
    const int quad = lane >> 4, c = lane & 15;

    __shared__ __align__(16) f16 Ks[64][72];
    __shared__ __align__(16) f16 Vts[64][72];
    __shared__ __align__(16) f16 Pw[4][32][72];
    __shared__ float tab[NREL];

    const size_t base = (size_t)bh << 16;

    for (int i = tid; i < NREL; i += 256) tab[i] = Tab[h * NREL + i];

    const int qg0 = q0 + (w << 5);
    half8 Aq[2][2];
#pragma unroll
    for (int s = 0; s < 2; ++s) {
        const f16* qp = Q + base + (size_t)(qg0 + s * 16 + c) * 64 + quad * 8;
        Aq[s][0] = *reinterpret_cast<const half8*>(qp);
        Aq[s][1] = *reinterpret_cast<const half8*>(qp + 32);
    }

    floatx4 o[2][4] = {};
    float l_part[2][4] = {};

    const int* rp = RPE + (size_t)(qg0 + (quad << 2)) * 1024 + c;

    const int sr = tid >> 2, so = (tid & 3) << 4;
    const f16* kbase = K  + base + (size_t)sr * 64 + so;
    const f16* vbase = Vt + base + (size_t)sr * 1024 + so;

    uint4 pk0 = *reinterpret_cast<const uint4*>(kbase);
    uint4 pk1 = *reinterpret_cast<const uint4*>(kbase + 8);
    uint4 pv0 = *reinterpret_cast<const uint4*>(vbase);
    uint4 pv1 = *reinterpret_cast<const uint4*>(vbase + 8);

    for (int j0 = 0; j0 < L_SEQ; j0 += 64) {
        __syncthreads();
        *reinterpret_cast<uint4*>(&Ks[sr][so])      = pk0;
        *reinterpret_cast<uint4*>(&Ks[sr][so + 8])  = pk1;
        *reinterpret_cast<uint4*>(&Vts[sr][so])     = pv0;
        *reinterpret_cast<uint4*>(&Vts[sr][so + 8]) = pv1;
        __syncthreads();

        if (j0 + 64 < L_SEQ) {
            const f16* kn = kbase + (size_t)(j0 + 64) * 64;
            const f16* vn = vbase + (j0 + 64);
            pk0 = *reinterpret_cast<const uint4*>(kn);
            pk1 = *reinterpret_cast<const uint4*>(kn + 8);
            pv0 = *reinterpret_cast<const uint4*>(vn);
            pv1 = *reinterpret_cast<const uint4*>(vn + 8);
        }

        int idx[2][4][4];
#pragma unroll
        for (int s = 0; s < 2; ++s)
#pragma unroll
            for (int r = 0; r < 4; ++r)
#pragma unroll
                for (int nt = 0; nt < 4; ++nt)
                    idx[s][r][nt] = rp[(size_t)(s * 16 + r) * 1024 + j0 + nt * 16];

        floatx4 sc[2][4];
#pragma unroll
        for (int nt = 0; nt < 4; ++nt) {
            const half8 b0 = *reinterpret_cast<const half8*>(&Ks[nt * 16 + c][quad * 8]);
            const half8 b1 = *reinterpret_cast<const half8*>(&Ks[nt * 16 + c][32 + quad * 8]);
            floatx4 t0 = {}, t1 = {};
            t0 = __builtin_amdgcn_mfma_f32_16x16x32_f16(Aq[0][0], b0, t0, 0, 0, 0);
            t0 = __builtin_amdgcn_mfma_f32_16x16x32_f16(Aq[0][1], b1, t0, 0, 0, 0);
            t1 = __builtin_amdgcn_mfma_f32_16x16x32_f16(Aq[1][0], b0, t1, 0, 0, 0);
            t1 = __builtin_amdgcn_mfma_f32_16x16x32_f16(Aq[1][1], b1, t1, 0, 0, 0);
            sc[0][nt] = t0; sc[1][nt] = t1;
        }

#pragma unroll
        for (int s = 0; s < 2; ++s)
#pragma unroll
            for (int r = 0; r < 4; ++r) {
                float rs = 0.0f;
#pragma unroll
                for (int nt = 0; nt < 4; ++nt) {
                    const float p = __expf(sc[s][nt][r] + tab[idx[s][r][nt]]);
                    rs += p;
                    Pw[w][s * 16 + quad * 4 + r][nt * 16 + c] = (f16)p;
                }
                l_part[s][r] += rs;
            }

        half8 vb[4][2];
#pragma unroll
        for (int nt = 0; nt < 4; ++nt) {
            vb[nt][0] = *reinterpret_cast<const half8*>(&Vts[nt * 16 + c][quad * 8]);
            vb[nt][1] = *reinterpret_cast<const half8*>(&Vts[nt * 16 + c][32 + quad * 8]);
        }
#pragma unroll
        for (int s = 0; s < 2; ++s) {
            const half8 Ap0 = *reinterpret_cast<const half8*>(&Pw[w][s * 16 + c][quad * 8]);
            const half8 Ap1 = *reinterpret_cast<const half8*>(&Pw[w][s * 16 + c][32 + quad * 8]);
#pragma unroll
            for (int nt = 0; nt < 4; ++nt) {
                o[s][nt] = __builtin_amdgcn_mfma_f32_16x16x32_f16(Ap0, vb[nt][0], o[s][nt], 0, 0, 0);
                o[s][nt] = __builtin_amdgcn_mfma_f32_16x16x32_f16(Ap1, vb[nt][1], o[s][nt], 0, 0, 0);
            }
        }
    }

#pragma unroll
    for (int s = 0; s < 2; ++s)
#pragma unroll
        for (int r = 0; r < 4; ++r) {
            float l = l_part[s][r];
            l += __shfl_xor(l, 1); l += __shfl_xor(l, 2);
            l += __shfl_xor(l, 4); l += __shfl_xor(l, 8);
            const float inv = 1.0f / l;
            const int lrow = qg0 + s * 16 + quad * 4 + r;
            f16* dp = CTX + ((size_t)(lrow * 16 + b)) * 512 + h * 64;
#pragma unroll
            for (int nt = 0; nt < 4; ++nt)
                dp[nt * 16 + c] = (f16)(o[s][nt][r] * inv);
        }
}

// ---------------------------------------------------------------------------
// Stage 4: out_proj MFMA GEMM. 512 blocks, XCD-swizzled.
// A = CTX (f16, DMA direct); B = W (fp32, DMA + read-path convert).
// ---------------------------------------------------------------------------
__global__ __launch_bounds__(256) void out_kernel(
    const f16* __restrict__ X, const float* __restrict__ W, const float* __restrict__ Bias,
    float* __restrict__ Out)
{
    // swizzle: 16 m-groups per XCD, 4 f-tiles per group on same XCD
    const int flat = blockIdx.x;
    const int xcd  = flat & 7;
    const int slot = flat >> 3;            // 0..63
    const int m    = xcd * 16 + (slot >> 2);   // 0..127
    const int f0   = (slot & 3) << 7;
    const int n0   = m << 7;

    // A: f16 tile 128 x 32 (64 B/row, 4 chunks). B: fp32 tile 128 x 32 (128 B/row).
    __shared__ __align__(16) f16   As[128 * 32];
    __shared__ __align__(16) float Bs[128 * 32];

    const int tid  = threadIdx.x;
    const int w    = tid >> 6;
    const int lane = tid & 63;
    const int quad = lane >> 4, c = lane & 15;
    const int wm = (w >> 1) << 6, wn = (w & 1) << 6;

    // A staging: issue i covers rows i*64 + w*16 + (lane>>2); slot lane&3 holds
    // logical chunk (lane&3)^((lane>>3)&3)   [f16 swizzle: slot = c ^ ((row>>1)&3)]
    const int ar  = lane >> 2;                       // 0..15
    const int ac  = (lane & 3) ^ ((lane >> 3) & 3);  // source chunk (8 f16)
    const f16* Xg = X + (size_t)(n0 + (w << 4) + ar) * E_DIM + (ac << 3);

    // B staging: same as qkv (fp32, slot = c ^ (row&7))
    const int lr = lane >> 3;
    const int lc = (lane & 7) ^ lr;
    const float* Wg = W + (size_t)(f0 + (w << 3) + lr) * E_DIM + (lc << 2);

    // read swizzles
    const int sa = ((quad ^ ((c >> 1) & 3)) << 3);   // f16 elem offset in A row
    const int sb0 = (((quad << 1) ^ (c & 7)) << 2);  // f32 elem offset in B row
    const int sb1 = sb0 ^ 4;

    floatx4 acc[4][4] = {};

    for (int k0 = 0; k0 < E_DIM; k0 += 32) {
        __syncthreads();
#pragma unroll
        for (int i = 0; i < 2; ++i)
            gl_lds16(Xg + (size_t)i * (64 * E_DIM) + k0, &As[((i << 6) + (w << 4)) << 5]);
#pragma unroll
        for (int i = 0; i < 4; ++i)
            gl_lds16(Wg + (size_t)i * (32 * E_DIM) + k0, &Bs[((i << 5) + (w << 3)) << 5]);
        __syncthreads();

        half8 a[4], bfr[4];
#pragma unroll
        for (int mt = 0; mt < 4; ++mt) {
            const int r = (wm + mt * 16 + c) << 5;
            a[mt] = *reinterpret_cast<const half8*>(&As[r + sa]);
        }
#pragma unroll
        for (int nt = 0; nt < 4; ++nt) {
            const int r = (wn + nt * 16 + c) << 5;
            const float4 lo = *reinterpret_cast<const float4*>(&Bs[r + sb0]);
            const float4 hi = *reinterpret_cast<const float4*>(&Bs[r + sb1]);
            bfr[nt] = cvt8(lo, hi);
        }
#pragma unroll
        for (int mt = 0; mt < 4; ++mt)
#pragma unroll
            for (int nt = 0; nt < 4; ++nt)
                acc[mt][nt] = __builtin_amdgcn_mfma_f32_16x16x32_f16(a[mt], bfr[nt], acc[mt][nt], 0, 0, 0);
    }

#pragma unroll
    for (int nt = 0; nt < 4; ++nt) {
        const int f = f0 + wn + nt * 16 + c;
        const float bj = Bias[f];
#pragma unroll
        for (int mt = 0; mt < 4; ++mt) {
#pragma unroll
            for (int r = 0; r < 4; ++r) {
                const int n = n0 + wm + mt * 16 + quad * 4 + r;
                Out[(size_t)n * E_DIM + f] = acc[mt][nt][r] + bj;
            }
        }
    }
}

// ---------------------------------------------------------------------------
extern "C" void kernel_launch(void* const* d_in, const int* in_sizes, int n_in,
                              void* d_out, int out_size, void* d_ws, size_t ws_size,
                              hipStream_t stream) {
    const float* q_in = (const float*)d_in[0];
    const float* k_in = (const float*)d_in[1];
    const float* v_in = (const float*)d_in[2];
    const float* ipw  = (const float*)d_in[3];
    const float* ipb  = (const float*)d_in[4];
    const float* opw  = (const float*)d_in[5];
    const float* opb  = (const float*)d_in[6];
    const float* tab  = (const float*)d_in[7];
    const int*   rpe  = (const int*)d_in[8];
    float* out = (float*)d_out;

    f16* ws   = (f16*)d_ws;
    f16* Q    = ws;
    f16* K    = ws + 8388608;
    f16* Vt   = ws + 16777216;
    f16* Vtmp = ws + 25165824;
    f16* CTX  = ws + 25165824;

    qkv_kernel<<<dim3(1536), 256, 0, stream>>>(q_in, k_in, v_in, ipw, ipb, Q, K, Vtmp);
    transpose_v<<<dim3(16, 128), 256, 0, stream>>>(Vtmp, Vt);
    attn_kernel<<<dim3(8, 128), 256, 0, stream>>>(Q, K, Vt, rpe, tab, CTX);
    out_kernel<<<dim3(512), 256, 0, stream>>>(CTX, opw, opb, out);
}